// Round 2
// baseline (463.245 us; speedup 1.0000x reference)
//
#include <hip/hip_runtime.h>
#include <stdint.h>

// Problem constants (fixed by reference setup_inputs): x (32,384,56,56) fp32,
// weight (384,384) fp32, bias (384,) fp32. K=7 horizontal cyclic shifts.
#define B_   32
#define C_   384
#define H_   56
#define W_   56
#define HW_  (H_*W_)    // 3136
#define NWORD 6         // 384 / 64 bits

// dx per (c % 7): (c + 3) % 7 - 3  ->  {0,1,2,3,-3,-2,-1}
__device__ constexpr int dxtab[7] = {0, 1, 2, 3, -3, -2, -1};

// 7 edge patterns: w = 0,1,2, interior(3..52), 53,54,55.
// invalid-channel bitmasks + valid counts, computed at COMPILE time.
struct Masks {
    unsigned long long inv[7][NWORD];
    int nvalid[7];
};
constexpr Masks make_masks() {
    Masks m{};
    int wv[7] = {0, 1, 2, 3, 53, 54, 55};
    for (int p = 0; p < 7; ++p) {
        int nv = 0;
        for (int c = 0; c < C_; ++c) {
            int dx = (c + 3) % 7 - 3;
            int wp = wv[p] + dx;
            if (wp >= 0 && wp < W_) nv++;
            else m.inv[p][c >> 6] |= 1ull << (c & 63);
        }
        m.nvalid[p] = nv;
    }
    return m;
}
__device__ constexpr Masks MK = make_masks();

// ---------------------------------------------------------------------------
// Prep: pack sign(weight) into 6 uint64 per output channel via __ballot, and
// build C2[o][pat] = Nvalid(pat) + 2*popcount(wbits & invalid(pat)) + bias[o].
// Derivation: out = Nvalid - 2*Mismatch_valid + bias, and with invalid x-bits
// forced to 0: popcount(xm ^ w) = Mismatch_valid + popcount(w & ~mask), so
// out = C2[o][pat] - 2*popcount(xm ^ w).
// C2 layout is [o][pat] (stride 7) so the 7 per-lane pattern variants for a
// given o live in one 28 B span -> one cache line per vector load in the main
// kernel's o-loop.
// ---------------------------------------------------------------------------
__global__ __launch_bounds__(64) void prep_kernel(
        const float* __restrict__ weight, const float* __restrict__ bias,
        unsigned long long* __restrict__ pw, float* __restrict__ C2) {
    int o = blockIdx.x;
    int lane = threadIdx.x;
    unsigned long long words[NWORD];
#pragma unroll
    for (int k = 0; k < NWORD; ++k) {
        float v = weight[o * C_ + k * 64 + lane];
        words[k] = __ballot(v < 0.0f);   // bit c set <=> sign(weight)==-1
    }
    if (lane < NWORD) pw[o * NWORD + lane] = words[lane];
    if (lane < 7) {
        int wb = 0;
#pragma unroll
        for (int k = 0; k < NWORD; ++k)
            wb += __popcll(words[k] & MK.inv[lane][k]);
        C2[o * 7 + lane] = (float)(MK.nvalid[lane] + 2 * wb) + bias[o];
    }
}

// ---------------------------------------------------------------------------
// Main: block = 256 threads = 4 waves, handling 64 consecutive pixels.
//   lane (t&63)  -> pixel  (so global loads/stores are 256B-coalesced and
//                   weight reads are wave-uniform scalar loads)
//   wave (t>>6)  -> 96-channel slice of the o-loop (4x the wave-parallelism
//                   of one-thread-per-pixel; packing is duplicated across the
//                   4 waves but the x reads hit L1/L2)
// Each thread packs shifted sign(x) (invalid -> 0) into 6 uint64, then for its
// 96 output channels computes out = C2[o][pat] - 2*popcount(xw ^ wbits).
// ---------------------------------------------------------------------------
__global__ __launch_bounds__(256) void cyclefc_kernel(
        const float* __restrict__ x,
        const unsigned long long* __restrict__ pw,
        const float* __restrict__ C2,
        float* __restrict__ out) {
    int t = threadIdx.x;
    int lane = t & 63;
    int oc = t >> 6;                                 // 0..3, wave-uniform
    unsigned p = blockIdx.x * 64u + (unsigned)lane;  // pixel < 100352 exactly
    unsigned w = p % (unsigned)W_;                   // [0,56)
    unsigned bh = p / (unsigned)W_;
    unsigned h = bh % (unsigned)H_;
    unsigned b = bh / (unsigned)H_;

    const float* xb = x + (size_t)b * C_ * HW_ + h * W_;

    unsigned long long xw[NWORD];
    int cm = 0;  // c % 7, folded at compile time by full unroll
#pragma unroll
    for (int k = 0; k < NWORD; ++k) {
        unsigned long long bits = 0;
#pragma unroll
        for (int j = 0; j < 64; ++j) {
            int c = k * 64 + j;
            int dx = dxtab[cm];
            cm = (cm == 6) ? 0 : cm + 1;
            int wp = (int)w + dx;
            // branchless: clamp address (stays in-row, safe), mask sign bit
            int wpc = wp < 0 ? 0 : (wp > W_ - 1 ? W_ - 1 : wp);
            unsigned u = __float_as_uint(xb[(size_t)c * HW_ + wpc]);
            unsigned sb = (u >> 31) & ((unsigned)wp < (unsigned)W_ ? 1u : 0u);
            bits |= (unsigned long long)sb << j;
        }
        xw[k] = bits;
    }

    int pat = (w < 3u) ? (int)w : ((w >= 53u) ? (int)w - 49 : 3);
    float* op = out + (size_t)b * C_ * HW_ + h * W_ + w;

    const int obase = oc * (C_ / 4);                 // 96-channel slice
#pragma unroll 4
    for (int oi = 0; oi < C_ / 4; ++oi) {
        int o = obase + oi;
        const unsigned long long* wr = pw + o * NWORD;  // uniform -> s_load
        int U = 0;
#pragma unroll
        for (int k = 0; k < NWORD; ++k)
            U += __popcll(xw[k] ^ wr[k]);
        op[(size_t)o * HW_] = C2[o * 7 + pat] - 2.0f * (float)U;
    }
}

extern "C" void kernel_launch(void* const* d_in, const int* in_sizes, int n_in,
                              void* d_out, int out_size, void* d_ws, size_t ws_size,
                              hipStream_t stream) {
    const float* x      = (const float*)d_in[0];
    const float* weight = (const float*)d_in[1];
    const float* bias   = (const float*)d_in[2];
    float* out = (float*)d_out;

    unsigned long long* pw = (unsigned long long*)d_ws;              // 18432 B
    float* C2 = (float*)((char*)d_ws + C_ * NWORD * sizeof(unsigned long long));

    prep_kernel<<<dim3(C_), dim3(64), 0, stream>>>(weight, bias, pw, C2);

    const int npix = B_ * H_ * W_;          // 100352 = 1568 * 64
    cyclefc_kernel<<<dim3(npix / 64), dim3(256), 0, stream>>>(x, pw, C2, out);
}

// Round 3
// 274.671 us; speedup vs baseline: 1.6865x; 1.6865x over previous
//
#include <hip/hip_runtime.h>
#include <stdint.h>

// Problem constants (fixed by reference setup_inputs): x (32,384,56,56) fp32,
// weight (384,384) fp32, bias (384,) fp32. K=7 horizontal cyclic shifts.
#define B_   32
#define C_   384
#define H_   56
#define W_   56
#define HW_  (H_*W_)        // 3136
#define NP_  (B_*H_*W_)     // 100352 pixels = 392 * 256
#define NWORD 6             // 384 / 64 bits
#define PIXBLK 392          // NP_ / 256

// dx(c) = (c + 3) % 7 - 3  ->  c%7 = 0..6 : {0,1,2,3,-3,-2,-1}

// ---------------------------------------------------------------------------
// Compile-time tables.
// inv[pat][k]: bit c of word k set <=> channel c is out-of-bounds for edge
// pattern pat (pat = w for w<3, 3 for interior, w-49 for w>=53).
// invw[w][k]: same, indexed directly by w (for the pack kernel).
// ---------------------------------------------------------------------------
struct Masks {
    unsigned long long inv[7][NWORD];
    int nvalid[7];
};
constexpr Masks make_masks() {
    Masks m{};
    int wv[7] = {0, 1, 2, 3, 53, 54, 55};
    for (int p = 0; p < 7; ++p) {
        int nv = 0;
        for (int c = 0; c < C_; ++c) {
            int dx = (c + 3) % 7 - 3;
            int wp = wv[p] + dx;
            if (wp >= 0 && wp < W_) nv++;
            else m.inv[p][c >> 6] |= 1ull << (c & 63);
        }
        m.nvalid[p] = nv;
    }
    return m;
}
__device__ constexpr Masks MK = make_masks();

struct InvW { unsigned long long m[W_][NWORD]; };
constexpr InvW make_invw() {
    InvW t{};
    for (int w = 0; w < W_; ++w)
        for (int c = 0; c < C_; ++c) {
            int dx = (c + 3) % 7 - 3;
            int wp = w + dx;
            if (!(wp >= 0 && wp < W_)) t.m[w][c >> 6] |= 1ull << (c & 63);
        }
    return t;
}
__device__ constexpr InvW IVW = make_invw();

// ---------------------------------------------------------------------------
// Prep: pack sign(weight) into 6 uint64 per output channel via __ballot, and
// build C2[o][pat] = Nvalid(pat) + 2*popcount(wbits & inv(pat)) + bias[o].
// out = C2[o][pat] - 2*popcount(xm ^ wbits)  with invalid x-bits forced to 0.
// ---------------------------------------------------------------------------
__global__ __launch_bounds__(64) void prep_kernel(
        const float* __restrict__ weight, const float* __restrict__ bias,
        unsigned long long* __restrict__ pw, float* __restrict__ C2) {
    int o = blockIdx.x;
    int lane = threadIdx.x;
    unsigned long long words[NWORD];
#pragma unroll
    for (int k = 0; k < NWORD; ++k) {
        float v = weight[o * C_ + k * 64 + lane];
        words[k] = __ballot(v < 0.0f);   // bit c set <=> sign(weight)==-1
    }
    if (lane < NWORD) pw[o * NWORD + lane] = words[lane];
    if (lane < 7) {
        int wb = 0;
#pragma unroll
        for (int k = 0; k < NWORD; ++k)
            wb += __popcll(words[k] & MK.inv[lane][k]);
        C2[o * 7 + lane] = (float)(MK.nvalid[lane] + 2 * wb) + bias[o];
    }
}

// ---------------------------------------------------------------------------
// Kernel A: pack shifted sign(x) bits.  One thread per (pixel, word-of-64-
// channels).  k is wave-uniform (blockIdx-derived); the per-channel shift
// pattern is template-folded so dx and the bit position are compile-time.
// pk layout: [word][pixel]  ->  both A's stores and B's loads are coalesced.
// ---------------------------------------------------------------------------
template <int K>
__device__ __forceinline__ unsigned long long pack_word(
        const float* __restrict__ xb, int w) {
    constexpr int dxt[7] = {0, 1, 2, 3, -3, -2, -1};
    unsigned long long bits = 0;
#pragma unroll
    for (int j = 0; j < 64; ++j) {
        int dx = dxt[(K * 64 + j) % 7];          // folds after unroll
        int wp = w + dx;
        int wpc = wp < 0 ? 0 : (wp > W_ - 1 ? W_ - 1 : wp);  // clamp (masked later)
        unsigned u = __float_as_uint(
            __builtin_nontemporal_load(&xb[(size_t)j * HW_ + wpc]));
        bits |= (unsigned long long)(u >> 31) << j;
    }
    return bits & ~IVW.m[w][K];                  // zero out-of-bounds channels
}

__global__ __launch_bounds__(256) void pack_kernel(
        const float* __restrict__ x, unsigned long long* __restrict__ pk) {
    int k = blockIdx.x / PIXBLK;                              // word, uniform
    unsigned p = (blockIdx.x % PIXBLK) * 256u + threadIdx.x;  // pixel
    unsigned b = p / (unsigned)HW_;
    unsigned r = p % (unsigned)HW_;
    unsigned h = r / (unsigned)W_;
    int w = (int)(r % (unsigned)W_);

    const float* xb = x + ((size_t)b * C_ + k * 64) * HW_ + h * W_;

    unsigned long long bits;
    switch (k) {
        case 0: bits = pack_word<0>(xb, w); break;
        case 1: bits = pack_word<1>(xb, w); break;
        case 2: bits = pack_word<2>(xb, w); break;
        case 3: bits = pack_word<3>(xb, w); break;
        case 4: bits = pack_word<4>(xb, w); break;
        default: bits = pack_word<5>(xb, w); break;
    }
    pk[(size_t)k * NP_ + p] = bits;
}

// ---------------------------------------------------------------------------
// Kernel B: binary GEMM.  One thread per (pixel, 48-output-channel chunk).
// Weights are wave-uniform -> scalar loads; pk reads are coalesced and served
// from L2/L3 (4.8 MB total, read 8x); out stores are nontemporal (write-once).
// ---------------------------------------------------------------------------
__global__ __launch_bounds__(256) void bgemm_kernel(
        const unsigned long long* __restrict__ pk,
        const unsigned long long* __restrict__ pw,
        const float* __restrict__ C2,
        float* __restrict__ out) {
    int oc = blockIdx.x / PIXBLK;                             // o-chunk 0..7
    unsigned p = (blockIdx.x % PIXBLK) * 256u + threadIdx.x;  // pixel
    unsigned b = p / (unsigned)HW_;
    unsigned w = p % (unsigned)W_;
    int pat = (w < 3u) ? (int)w : ((w >= 53u) ? (int)w - 49 : 3);

    unsigned long long xw[NWORD];
#pragma unroll
    for (int k = 0; k < NWORD; ++k)
        xw[k] = pk[(size_t)k * NP_ + p];

    float* op = out + p + (size_t)b * (C_ - 1) * HW_;  // == b*C*HW + h*W + w

    const int obase = oc * (C_ / 8);                   // 48 channels
#pragma unroll 4
    for (int oi = 0; oi < C_ / 8; ++oi) {
        int o = obase + oi;
        const unsigned long long* wr = pw + o * NWORD; // uniform -> s_load
        int U = 0;
#pragma unroll
        for (int k = 0; k < NWORD; ++k)
            U += __popcll(xw[k] ^ wr[k]);
        float v = C2[o * 7 + pat] - 2.0f * (float)U;
        __builtin_nontemporal_store(v, &op[(size_t)o * HW_]);
    }
}

// ---------------------------------------------------------------------------
// Fallback (round-1 kernel, known passing, 122 us) if workspace is too small
// for the 4.8 MB packed intermediate.
// ---------------------------------------------------------------------------
__global__ __launch_bounds__(256) void cyclefc_fb_kernel(
        const float* __restrict__ x,
        const unsigned long long* __restrict__ pw,
        const float* __restrict__ C2,
        float* __restrict__ out) {
    unsigned p = blockIdx.x * 256u + threadIdx.x;
    unsigned w = p % (unsigned)W_;
    unsigned bh = p / (unsigned)W_;
    unsigned h = bh % (unsigned)H_;
    unsigned b = bh / (unsigned)H_;
    const float* xb = x + (size_t)b * C_ * HW_ + h * W_;

    constexpr int dxt[7] = {0, 1, 2, 3, -3, -2, -1};
    unsigned long long xw[NWORD];
#pragma unroll
    for (int k = 0; k < NWORD; ++k) {
        unsigned long long bits = 0;
#pragma unroll
        for (int j = 0; j < 64; ++j) {
            int dx = dxt[(k * 64 + j) % 7];
            int wp = (int)w + dx;
            int wpc = wp < 0 ? 0 : (wp > W_ - 1 ? W_ - 1 : wp);
            unsigned u = __float_as_uint(xb[(size_t)(k * 64 + j) * HW_ + wpc]);
            bits |= (unsigned long long)(u >> 31) << j;
        }
        xw[k] = bits & ~IVW.m[w][k];
    }
    int pat = (w < 3u) ? (int)w : ((w >= 53u) ? (int)w - 49 : 3);
    float* op = out + (size_t)b * C_ * HW_ + h * W_ + w;
#pragma unroll 4
    for (int o = 0; o < C_; ++o) {
        const unsigned long long* wr = pw + o * NWORD;
        int U = 0;
#pragma unroll
        for (int k = 0; k < NWORD; ++k)
            U += __popcll(xw[k] ^ wr[k]);
        op[(size_t)o * HW_] = C2[o * 7 + pat] - 2.0f * (float)U;
    }
}

extern "C" void kernel_launch(void* const* d_in, const int* in_sizes, int n_in,
                              void* d_out, int out_size, void* d_ws, size_t ws_size,
                              hipStream_t stream) {
    const float* x      = (const float*)d_in[0];
    const float* weight = (const float*)d_in[1];
    const float* bias   = (const float*)d_in[2];
    float* out = (float*)d_out;

    // ws layout: pw (18432 B) | C2 (10752 B) | pad to 32768 | pk (4816896 B)
    unsigned long long* pw = (unsigned long long*)d_ws;
    float* C2 = (float*)((char*)d_ws + C_ * NWORD * sizeof(unsigned long long));
    unsigned long long* pk = (unsigned long long*)((char*)d_ws + 32768);
    const size_t need = 32768 + (size_t)NWORD * NP_ * sizeof(unsigned long long);

    prep_kernel<<<dim3(C_), dim3(64), 0, stream>>>(weight, bias, pw, C2);

    if (ws_size >= need) {
        pack_kernel<<<dim3(PIXBLK * NWORD), dim3(256), 0, stream>>>(x, pk);
        bgemm_kernel<<<dim3(PIXBLK * 8), dim3(256), 0, stream>>>(pk, pw, C2, out);
    } else {
        cyclefc_fb_kernel<<<dim3(NP_ / 256), dim3(256), 0, stream>>>(x, pw, C2, out);
    }
}